// Round 5
// baseline (1411.821 us; speedup 1.0000x reference)
//
#include <hip/hip_runtime.h>
#include <stdint.h>

typedef __bf16 bf16_t;
typedef __bf16 bf16x8 __attribute__((ext_vector_type(8)));
typedef float f32x4 __attribute__((ext_vector_type(4)));

#define MFMA16(a, b, c) __builtin_amdgcn_mfma_f32_16x16x32_bf16(a, b, c, 0, 0, 0)

__device__ __forceinline__ void gload_lds16(const bf16_t* g, bf16_t* l) {
  __builtin_amdgcn_global_load_lds(
      (const __attribute__((address_space(1))) void*)g,
      (__attribute__((address_space(3))) void*)l, 16, 0, 0);
}

__device__ __forceinline__ int sw4(int i) {  // nibble swap of 0..15
  return ((i & 3) << 2) | ((i >> 2) & 3);
}

// ---------------------------------------------------------------------------
// Transpose+convert both weights in one launch. blocks 0..767: qkv_w [256,768];
// blocks 768..1023: proj_w [256,256].
__global__ __launch_bounds__(256) void cvt_w2_k(const float* __restrict__ w1,
                                                bf16_t* __restrict__ o1,
                                                const float* __restrict__ w2,
                                                bf16_t* __restrict__ o2) {
  int blk = blockIdx.x, k = threadIdx.x;
  if (blk < 768) {
    o1[(size_t)blk * 256 + k] = (bf16_t)w1[(size_t)k * 768 + blk];
  } else {
    int n = blk - 768;
    o2[(size_t)n * 256 + k] = (bf16_t)w2[(size_t)k * 256 + n];
  }
}

// ---------------------------------------------------------------------------
// Precompute cmb[w][h][112][112] = bias_table[rel(i,j), h] + mask[w][i][j],
// padded: j in [98,112) -> -1e30 (absorbs the old per-element select AND the
// k-ghost masking); i in [98,112) -> clamped-row finite values (outputs for
// those rows are discarded). Stored in d_out used as scratch (gemm2 fully
// overwrites d_out afterwards). Block 0 also zeroes the 14 ghost qkv rows
// past row 200703 so b=2047's out-of-batch Q/K reads are 0.0 (not garbage).
__global__ __launch_bounds__(256) void prep_cmb(const float* __restrict__ mask,
                                                const float* __restrict__ btab,
                                                float* __restrict__ cmb,
                                                bf16_t* __restrict__ qkv_ghost) {
  __shared__ int sU[112];
  __shared__ float sT[512];
  const int tid = threadIdx.x;
  const int w = blockIdx.x >> 3, h = blockIdx.x & 7;
  if (tid < 112) {
    int n = tid;
    int d = n / 49, r = n - d * 49;
    int hh = r / 7, ww = r - hh * 7;
    sU[tid] = (n < 98) ? (d * 169 + hh * 13 + ww) : 0;
  }
  for (int i = tid; i < 512; i += 256) sT[i] = (i < 507) ? btab[i * 8 + h] : 0.f;
  __syncthreads();
  const float* mp = mask + (size_t)w * 9604;
  float* cb = cmb + (size_t)blockIdx.x * 12544;
  for (int idx = tid; idx < 12544; idx += 256) {
    int i = idx / 112, j = idx - i * 112;
    float v;
    if (j < 98)
      v = sT[253 + sU[i] - sU[j]] + mp[(i < 98 ? i : 97) * 98 + j];
    else
      v = -1e30f;
    cb[idx] = v;
  }
  if (blockIdx.x == 0) {
    bf16x8 z = {};
    for (int t = tid; t < 14 * 768 / 8; t += 256)
      *(bf16x8*)(qkv_ghost + (size_t)t * 8) = z;
  }
}

// ---------------------------------------------------------------------------
// GEMM: C[M, ncols-slice] = A[M,256] @ B  with BT[n][k] pre-transposed bf16.
// AF32: A is fp32; staged via registers (load f32 -> cvt bf16 -> ds_write to
// the same swizzled sA layout). Fuses the x->bf16 pass into gemm1.
// XCD chunk-swizzle (bijective, nwg%8==0): XCD x computes a contiguous run of
// tile-space; runs of gridDim.x consecutive tiles share one A panel -> L2 hit.
template <bool AF32>
__global__ __launch_bounds__(256) void gemm256_t(const void* __restrict__ Av,
                                                 const bf16_t* __restrict__ BT,
                                                 int ncols,
                                                 bf16_t* __restrict__ outb,
                                                 float* __restrict__ outf,
                                                 const float* __restrict__ bias) {
  __shared__ __align__(16) bf16_t sA[128 * 64];
  __shared__ __align__(16) bf16_t sB[128 * 64];
  const int tid = threadIdx.x;
  const int lane = tid & 63, wave = tid >> 6;
  const int lm = lane & 15, quad = lane >> 4;

  int nwg = gridDim.x * gridDim.y;
  int L = blockIdx.y * gridDim.x + blockIdx.x;
  if ((nwg & 7) == 0) {
    int cpx = nwg >> 3;
    L = (L & 7) * cpx + (L >> 3);
  }
  const int bx = L % gridDim.x, by = L / gridDim.x;

  const int mBase = by * 128;
  const int nBase = bx * 128;
  const int wm = (wave >> 1) * 64, wn = (wave & 1) * 64;

  f32x4 acc[4][4];
#pragma unroll
  for (int i = 0; i < 4; i++)
#pragma unroll
    for (int j = 0; j < 4; j++) acc[i][j] = {0.f, 0.f, 0.f, 0.f};

  const bf16_t* Ab = AF32 ? nullptr : (const bf16_t*)Av + (size_t)mBase * 256;
  const float* Af = AF32 ? (const float*)Av + (size_t)mBase * 256 : nullptr;
  const bf16_t* Bb = BT + (size_t)nBase * 256;

  for (int kb = 0; kb < 4; ++kb) {
    const int k0 = kb * 64;
    if constexpr (AF32) {
      f32x4 fa[4][2];
#pragma unroll
      for (int it = 0; it < 4; ++it) {
        int cid = it * 256 + wave * 64 + lane;
        int row = cid >> 3, kcp = cid & 7;
        int kcl = kcp ^ (row & 7);
        const f32x4* src = (const f32x4*)(Af + (size_t)row * 256 + k0 + kcl * 8);
        fa[it][0] = src[0];
        fa[it][1] = src[1];
      }
#pragma unroll
      for (int it = 0; it < 4; ++it) {
        int cid = it * 256 + wave * 64 + lane;
        int row = cid >> 3, kcp = cid & 7;
        bf16_t* dstB = sB + (it * 256 + wave * 64) * 8;
        gload_lds16(Bb + (size_t)row * 256 + k0 + (kcp ^ (row & 7)) * 8, dstB);
        bf16x8 o = {(bf16_t)fa[it][0][0], (bf16_t)fa[it][0][1],
                    (bf16_t)fa[it][0][2], (bf16_t)fa[it][0][3],
                    (bf16_t)fa[it][1][0], (bf16_t)fa[it][1][1],
                    (bf16_t)fa[it][1][2], (bf16_t)fa[it][1][3]};
        *(bf16x8*)(sA + (size_t)cid * 8) = o;
      }
    } else {
#pragma unroll
      for (int it = 0; it < 4; ++it) {
        int cid = it * 256 + wave * 64 + lane;
        int row = cid >> 3, kcp = cid & 7;
        int kcl = kcp ^ (row & 7);
        bf16_t* dstA = sA + (it * 256 + wave * 64) * 8;  // wave-uniform base
        bf16_t* dstB = sB + (it * 256 + wave * 64) * 8;
        gload_lds16(Ab + (size_t)row * 256 + k0 + kcl * 8, dstA);
        gload_lds16(Bb + (size_t)row * 256 + k0 + kcl * 8, dstB);
      }
    }
    __syncthreads();
#pragma unroll
    for (int kk = 0; kk < 64; kk += 32) {
      int c = (kk >> 3) + quad;
      bf16x8 af[4], bfr[4];
#pragma unroll
      for (int mt = 0; mt < 4; mt++) {
        int m = wm + mt * 16 + lm;
        af[mt] = *(const bf16x8*)(sA + m * 64 + ((c ^ (m & 7)) << 3));
      }
#pragma unroll
      for (int nt = 0; nt < 4; nt++) {
        int n = wn + nt * 16 + lm;
        bfr[nt] = *(const bf16x8*)(sB + n * 64 + ((c ^ (n & 7)) << 3));
      }
#pragma unroll
      for (int mt = 0; mt < 4; mt++)
#pragma unroll
        for (int nt = 0; nt < 4; nt++)
          acc[mt][nt] = MFMA16(af[mt], bfr[nt], acc[mt][nt]);
    }
    __syncthreads();
  }

  if (outb) {
#pragma unroll
    for (int mt = 0; mt < 4; mt++)
#pragma unroll
      for (int nt = 0; nt < 4; nt++) {
        int col = nBase + wn + nt * 16 + lm;
        int rbase = mBase + wm + mt * 16 + quad * 4;
#pragma unroll
        for (int r = 0; r < 4; r++)
          outb[(size_t)(rbase + r) * ncols + col] = (bf16_t)acc[mt][nt][r];
      }
  } else {
#pragma unroll
    for (int mt = 0; mt < 4; mt++)
#pragma unroll
      for (int nt = 0; nt < 4; nt++) {
        int col = nBase + wn + nt * 16 + lm;
        float bv = bias[col];
        int rbase = mBase + wm + mt * 16 + quad * 4;
#pragma unroll
        for (int r = 0; r < 4; r++)
          outf[(size_t)(rbase + r) * ncols + col] = acc[mt][nt][r] + bv;
      }
  }
}

// ---------------------------------------------------------------------------
// Fused window attention, v7: round-4 body + cmb epilogue + 4 b-iterations.
// Grid 4096 blocks, 256 threads. Decode keeps sibling heads (sharing every
// 128B qkv line) on the same XCD at dispatch distance 8. Each block runs
// b = b0 + 512*it, it=0..3: same b&63 (mask window) and same h -> the 49KB
// cmb slice is L1/L2-hot after iteration 0, and setup (sVT pads, sP ghost
// chunks) is amortized 4x. No cross-iteration register state (round-3's
// spill lesson). Epilogue is one fmaf + one coalesced f32 load per element:
// bias-gather (the 1.4e7 bank-conflict source), mask load, clamps and the
// j-select are all folded into cmb. Ghost qkv rows are zeroed by prep_cmb,
// so cmb's -1e30 columns mask k>=98 with no select.
__global__ __launch_bounds__(256, 4) void attn_win(
    const bf16_t* __restrict__ qkv, const float* __restrict__ cmb,
    bf16_t* __restrict__ y) {
  __shared__ __align__(16) bf16_t sP[112 * 128];
  __shared__ __align__(16) bf16_t sVT[32 * 128];

  const int tid = threadIdx.x;
  const int L = blockIdx.x;
  const int qd = L >> 4, rr = L & 15;
  const int g = rr >> 3, x = rr & 7;
  const int bidx = qd * 8 + x;
  const int b0 = bidx >> 2;
  const int h = ((bidx & 3) << 1) | g;
  const int lane = tid & 63, wave = tid >> 6;
  const int lm = lane & 15, quad = lane >> 4;

  // ---- one-time setup ----
  // sP ghost chunks (k-pad cols 112..127 = swizzled chunks c2 in {14,15});
  // P-stores only ever write c2<=13, so these stay zero across iterations.
  if (tid < 224) {
    int i = tid >> 1, c2 = 14 + (tid & 1);
    uint4 z = {0, 0, 0, 0};
    *(uint4*)(sP + i * 128 + ((c2 ^ sw4(i & 15)) << 3)) = z;
  }
  // sVT pad cols j in [98,128)
  for (int idx = tid; idx < 1024; idx += 256) {
    int d = idx >> 5, j = 96 + (idx & 31);
    if (j >= 98)
      sVT[d * 128 + (((j >> 3) ^ sw4(d & 15)) << 3) + (j & 7)] = (bf16_t)0.f;
  }

  const float* cb = cmb + (size_t)((b0 & 63) * 8 + h) * 12544;
  const float scale = 0.17677669529663687f;

  for (int it = 0; it < 4; ++it) {
    const int b = b0 + it * 512;
    const bf16_t* qb = qkv + (size_t)b * 75264 + h * 32;

    if (it) __syncthreads();  // sVT WAR vs previous iteration's PV reads

    // ---- V scatter ----
    {
      int j = tid & 127, hf = tid >> 7;
      if (j < 98) {
#pragma unroll
        for (int t = 0; t < 2; t++) {
          int dc = hf + 2 * t;
          bf16x8 v8 = *(const bf16x8*)(qb + (size_t)j * 768 + 512 + dc * 8);
#pragma unroll
          for (int e = 0; e < 8; e++) {
            int d = dc * 8 + e;
            sVT[d * 128 + (((j >> 3) ^ sw4(d & 15)) << 3) + (j & 7)] = v8[e];
          }
        }
      }
    }
    __syncthreads();

    // ---- QK^T: wave computes row-tiles rt = wave, wave+4 ----
    bf16x8 kf[7];
#pragma unroll
    for (int ct = 0; ct < 7; ct++)
      kf[ct] =
          *(const bf16x8*)(qb + (size_t)(ct * 16 + lm) * 768 + 256 + quad * 8);

    f32x4 s4[2][7];
#pragma unroll
    for (int rti = 0; rti < 2; rti++) {
      int rt = wave + rti * 4;
      if (rt <= 6) {
        bf16x8 qf =
            *(const bf16x8*)(qb + (size_t)(rt * 16 + lm) * 768 + quad * 8);
#pragma unroll
        for (int ct = 0; ct < 7; ct++) {
          f32x4 z = {0.f, 0.f, 0.f, 0.f};
          s4[rti][ct] = MFMA16(qf, kf[ct], z);
        }
      }
    }

    // ---- epilogue: s*scale + cmb; softmax; P store ----
    float inv[2][4];
#pragma unroll
    for (int rti = 0; rti < 2; rti++) {
      int rt = wave + rti * 4;
      if (rt > 6) continue;
      int ib = rt * 16 + quad * 4;
#pragma unroll
      for (int ct = 0; ct < 7; ct++) {
        int j = ct * 16 + lm;
#pragma unroll
        for (int r = 0; r < 4; r++)
          s4[rti][ct][r] = fmaf(s4[rti][ct][r], scale, cb[(ib + r) * 112 + j]);
      }
#pragma unroll
      for (int r = 0; r < 4; r++) {
        float mx = s4[rti][0][r];
#pragma unroll
        for (int ct = 1; ct < 7; ct++) mx = fmaxf(mx, s4[rti][ct][r]);
#pragma unroll
        for (int o = 1; o < 16; o <<= 1) mx = fmaxf(mx, __shfl_xor(mx, o));
        float sum = 0.f;
#pragma unroll
        for (int ct = 0; ct < 7; ct++) {
          float e = __expf(s4[rti][ct][r] - mx);
          s4[rti][ct][r] = e;
          sum += e;
        }
#pragma unroll
        for (int o = 1; o < 16; o <<= 1) sum += __shfl_xor(sum, o);
        inv[rti][r] = 1.f / sum;
      }
      // store P bf16, swizzled: conflict-free column-wise stores
#pragma unroll
      for (int ct = 0; ct < 7; ct++) {
        int c2 = 2 * ct + (lm >> 3);
        int j7 = lm & 7;
#pragma unroll
        for (int r = 0; r < 4; r++) {
          int i = ib + r;
          sP[i * 128 + ((c2 ^ (4 * r + quad)) << 3) + j7] =
              (bf16_t)s4[rti][ct][r];
        }
      }
    }
    // No barrier: PV reads only this wave's own sP rows (wave-partitioned),
    // and sVT was synced after the scatter above.

    // ---- O = P V (K padded to 128 with zero P cols), scale by 1/sum ----
    bf16x8 vf[2][4];
#pragma unroll
    for (int dt = 0; dt < 2; dt++)
#pragma unroll
      for (int kk = 0; kk < 4; kk++) {
        int d = dt * 16 + lm;
        vf[dt][kk] = *(const bf16x8*)(sVT + d * 128 +
                                      (((4 * kk + quad) ^ sw4(lm)) << 3));
      }
    bf16_t* yb = y + (size_t)b * 98 * 256 + h * 32;
#pragma unroll
    for (int rti = 0; rti < 2; rti++) {
      int rt = wave + rti * 4;
      if (rt > 6) continue;
      bf16x8 af[4];
#pragma unroll
      for (int kk = 0; kk < 4; kk++) {
        int i = rt * 16 + lm;
        af[kk] =
            *(const bf16x8*)(sP + i * 128 + (((4 * kk + quad) ^ sw4(lm)) << 3));
      }
#pragma unroll
      for (int dt = 0; dt < 2; dt++) {
        f32x4 o = {0.f, 0.f, 0.f, 0.f};
#pragma unroll
        for (int kk = 0; kk < 4; kk++) o = MFMA16(af[kk], vf[dt][kk], o);
#pragma unroll
        for (int r = 0; r < 4; r++) {
          int i = rt * 16 + quad * 4 + r;
          if (i < 98)
            yb[(size_t)i * 256 + dt * 16 + lm] = (bf16_t)(o[r] * inv[rti][r]);
        }
      }
    }
  }
}

// ---------------------------------------------------------------------------
extern "C" void kernel_launch(void* const* d_in, const int* in_sizes, int n_in,
                              void* d_out, int out_size, void* d_ws,
                              size_t ws_size, hipStream_t stream) {
  const float* x = (const float*)d_in[0];       // [2048, 98, 256]
  const float* mask = (const float*)d_in[1];    // [64, 98, 98]
  const float* qkv_w = (const float*)d_in[2];   // [256, 768]
  const float* proj_w = (const float*)d_in[3];  // [256, 256]
  const float* proj_b = (const float*)d_in[4];  // [256]
  const float* btab = (const float*)d_in[5];    // [507, 8]
  float* out = (float*)d_out;                   // [2048, 98, 256]

  char* ws = (char*)d_ws;
  bf16_t* qkv = (bf16_t*)ws;
  bf16_t* ybuf = (bf16_t*)(ws + 308281344);
  bf16_t* wT = (bf16_t*)(ws + 308281344 + 102760448);
  bf16_t* pT = (bf16_t*)(ws + 308281344 + 102760448 + 393216);
  // cmb lives in d_out (25.7 MB scratch); gemm2 fully overwrites d_out after.
  float* cmb = out;
  bf16_t* qkv_ghost = qkv + (size_t)200704 * 768;  // 14 pad rows for b=2047

  prep_cmb<<<512, 256, 0, stream>>>(mask, btab, cmb, qkv_ghost);
  cvt_w2_k<<<1024, 256, 0, stream>>>(qkv_w, wT, proj_w, pT);

  // gemm1: A = x (fp32, converted in-kernel), writes qkv bf16
  gemm256_t<true><<<dim3(6, 1568), 256, 0, stream>>>(x, wT, 768, qkv, nullptr,
                                                     nullptr);

  attn_win<<<4096, 256, 0, stream>>>(qkv, cmb, ybuf);

  // gemm2: A = ybuf (bf16), writes out fp32 + bias (overwrites cmb scratch)
  gemm256_t<false><<<dim3(2, 1568), 256, 0, stream>>>(ybuf, pT, 256, nullptr,
                                                      out, proj_b);
}